// Round 7
// baseline (159.235 us; speedup 1.0000x reference)
//
#include <hip/hip_runtime.h>
#include <hip/hip_bf16.h>
#include <math.h>

#define NQ   4096
#define DIMC 256
#define NHC  8
#define NPC  8
#define HDC  32
#define HC   64
#define WC   64
#define BC   4
#define WSTR 40   // LDS row stride (ushorts): 80 B, 16B-aligned

typedef __bf16 bf16x8 __attribute__((ext_vector_type(8)));
typedef __attribute__((ext_vector_type(4))) float f4;
typedef __attribute__((ext_vector_type(8))) short s8v;

__device__ __forceinline__ ushort f2bf(float f) {
  __hip_bfloat16 h = __float2bfloat16(f);
  union { __hip_bfloat16 h; ushort u; } c; c.h = h; return c.u;
}
__device__ __forceinline__ float bfu2f(ushort u) {
  union { unsigned i; float f; } c; c.i = ((unsigned)u) << 16; return c.f;
}
__device__ __forceinline__ float bflo(unsigned u) {
  union { unsigned i; float f; } c; c.i = u << 16; return c.f;
}
__device__ __forceinline__ float bfhi(unsigned u) {
  union { unsigned i; float f; } c; c.i = u & 0xffff0000u; return c.f;
}

union bfr8 { ushort u[8]; bf16x8 v; s8v s; };

// ---------------------------------------------------------------------------
// k_proj (merged): y=0 loc/att (split-precision, 3 MFMA passes),
//                  y=1 value projection (plain bf16).
// Block = 32-query n-tile x ALL output features (A read from HBM once).
// R4's BK=32 register-prefetch pipeline kept verbatim; W k-slab staged
// cooperatively per K-step (same total conversion work as R4, 1 block).
// ---------------------------------------------------------------------------
__global__ __launch_bounds__(256) void k_proj(
    const float* __restrict__ query, const float* __restrict__ value,
    const float* __restrict__ W_loc, const float* __restrict__ b_loc,
    const float* __restrict__ W_att, const float* __restrict__ b_att,
    const float* __restrict__ W_val, const float* __restrict__ b_val,
    float* __restrict__ loc, float* __restrict__ att,
    ushort* __restrict__ vproj) {
  __shared__ __align__(16) ushort smem[17920];  // 35.8 KB max (locatt path)
  const int tid = threadIdx.x, b = blockIdx.z, n0 = blockIdx.x * 32;
  const int lane = tid & 63, wid = tid >> 6;
  const int am = lane & 15, kq = (lane >> 4) * 8, row4 = (lane >> 4) * 4;
  const int an = tid & 31, akg = (tid >> 5) * 4;  // A staging coords

  if (blockIdx.y == 0) {
    // ================= loc/att: split-precision =================
    ushort* Ah = smem;            // 32 x WSTR
    ushort* Al = smem + 1280;
    ushort* Wh = smem + 2560;     // 192 x WSTR
    ushort* Wl = smem + 10240;
    const float* Xb = query + (size_t)b * DIMC * NQ + n0 + an;
    // W staging: thread covers 3 chunks of 8 (192 rows x 32 k total)
    int crow[3], ckp[3];
    const float* Wr[3];
#pragma unroll
    for (int i = 0; i < 3; ++i) {
      const int cc = tid * 3 + i;
      crow[i] = cc >> 2; ckp[i] = (cc & 3) * 8;
      Wr[i] = ((crow[i] < 128) ? (W_loc + (size_t)crow[i] * DIMC)
                               : (W_att + (size_t)(crow[i] - 128) * DIMC)) + ckp[i];
    }
    float ax[4];
    float4 wp[3][2];
#pragma unroll
    for (int j = 0; j < 4; ++j) ax[j] = Xb[(size_t)(akg + j) * NQ];
#pragma unroll
    for (int i = 0; i < 3; ++i) {
      wp[i][0] = *(const float4*)(Wr[i]);
      wp[i][1] = *(const float4*)(Wr[i] + 4);
    }
    const int o0w = wid * 48;
    f4 acc[2][3];
#pragma unroll
    for (int mi = 0; mi < 2; ++mi)
#pragma unroll
      for (int oj = 0; oj < 3; ++oj) acc[mi][oj] = (f4)0.f;

    for (int t = 0; t < 8; ++t) {
      __syncthreads();
      {
        ushort4 hh, ll;
        float a0 = ax[0], a1 = ax[1], a2 = ax[2], a3 = ax[3];
        hh.x = f2bf(a0); ll.x = f2bf(a0 - bfu2f(hh.x));
        hh.y = f2bf(a1); ll.y = f2bf(a1 - bfu2f(hh.y));
        hh.z = f2bf(a2); ll.z = f2bf(a2 - bfu2f(hh.z));
        hh.w = f2bf(a3); ll.w = f2bf(a3 - bfu2f(hh.w));
        *(ushort4*)(&Ah[an * WSTR + akg]) = hh;
        *(ushort4*)(&Al[an * WSTR + akg]) = ll;
#pragma unroll
        for (int i = 0; i < 3; ++i) {
          const float wt[8] = {wp[i][0].x, wp[i][0].y, wp[i][0].z, wp[i][0].w,
                               wp[i][1].x, wp[i][1].y, wp[i][1].z, wp[i][1].w};
          bfr8 bh, bl;
#pragma unroll
          for (int j = 0; j < 8; ++j) {
            ushort h = f2bf(wt[j]);
            bh.u[j] = h;
            bl.u[j] = f2bf(wt[j] - bfu2f(h));
          }
          *(s8v*)(&Wh[crow[i] * WSTR + ckp[i]]) = bh.s;
          *(s8v*)(&Wl[crow[i] * WSTR + ckp[i]]) = bl.s;
        }
      }
      if (t < 7) {
        const int k0 = (t + 1) * 32;
#pragma unroll
        for (int j = 0; j < 4; ++j) ax[j] = Xb[(size_t)(k0 + akg + j) * NQ];
#pragma unroll
        for (int i = 0; i < 3; ++i) {
          wp[i][0] = *(const float4*)(Wr[i] + k0);
          wp[i][1] = *(const float4*)(Wr[i] + k0 + 4);
        }
      }
      __syncthreads();
      bf16x8 ah[2], al[2];
#pragma unroll
      for (int mi = 0; mi < 2; ++mi) {
        ah[mi] = *(const bf16x8*)(&Ah[(mi * 16 + am) * WSTR + kq]);
        al[mi] = *(const bf16x8*)(&Al[(mi * 16 + am) * WSTR + kq]);
      }
#pragma unroll
      for (int oj = 0; oj < 3; ++oj) {
        bf16x8 bh = *(const bf16x8*)(&Wh[(o0w + oj * 16 + am) * WSTR + kq]);
        bf16x8 bl = *(const bf16x8*)(&Wl[(o0w + oj * 16 + am) * WSTR + kq]);
#pragma unroll
        for (int mi = 0; mi < 2; ++mi) {
          acc[mi][oj] = __builtin_amdgcn_mfma_f32_16x16x32_bf16(ah[mi], bh, acc[mi][oj], 0, 0, 0);
          acc[mi][oj] = __builtin_amdgcn_mfma_f32_16x16x32_bf16(al[mi], bh, acc[mi][oj], 0, 0, 0);
          acc[mi][oj] = __builtin_amdgcn_mfma_f32_16x16x32_bf16(ah[mi], bl, acc[mi][oj], 0, 0, 0);
        }
      }
    }
#pragma unroll
    for (int oj = 0; oj < 3; ++oj) {
      const int oA = o0w + oj * 16;   // 16-aligned, never straddles 128
      const bool isAtt = (oA >= 128);
      float* dstBase = isAtt ? att : loc;
      const float* bias = isAtt ? b_att : b_loc;
      const int ostride = isAtt ? 64 : 128;
      const int o = (isAtt ? oA - 128 : oA) + am;
      const float bv = bias[o];
#pragma unroll
      for (int mi = 0; mi < 2; ++mi) {
        const int nb = n0 + mi * 16 + row4;
#pragma unroll
        for (int r = 0; r < 4; ++r)
          dstBase[((size_t)b * NQ + nb + r) * ostride + o] = acc[mi][oj][r] + bv;
      }
    }
  } else {
    // ================= value projection =================
    ushort* As = smem;            // 32 x WSTR
    ushort* Ws = smem + 2560;     // 256 x WSTR
    const float* Xb = value + (size_t)b * DIMC * NQ + n0 + an;
    const float* Wr = W_val + (size_t)tid * DIMC;  // one row per thread

    float ax[4];
    float4 wp[4][2];
#pragma unroll
    for (int j = 0; j < 4; ++j) ax[j] = Xb[(size_t)(akg + j) * NQ];
#pragma unroll
    for (int c = 0; c < 4; ++c) {
      wp[c][0] = *(const float4*)(Wr + c * 8);
      wp[c][1] = *(const float4*)(Wr + c * 8 + 4);
    }
    const int o0w = wid * 64;
    f4 acc[2][4];
#pragma unroll
    for (int mi = 0; mi < 2; ++mi)
#pragma unroll
      for (int oj = 0; oj < 4; ++oj) acc[mi][oj] = (f4)0.f;

    for (int t = 0; t < 8; ++t) {
      __syncthreads();
      {
        ushort4 hh;
        hh.x = f2bf(ax[0]); hh.y = f2bf(ax[1]);
        hh.z = f2bf(ax[2]); hh.w = f2bf(ax[3]);
        *(ushort4*)(&As[an * WSTR + akg]) = hh;
#pragma unroll
        for (int c = 0; c < 4; ++c) {
          const float wt[8] = {wp[c][0].x, wp[c][0].y, wp[c][0].z, wp[c][0].w,
                               wp[c][1].x, wp[c][1].y, wp[c][1].z, wp[c][1].w};
          bfr8 bh;
#pragma unroll
          for (int j = 0; j < 8; ++j) bh.u[j] = f2bf(wt[j]);
          *(s8v*)(&Ws[tid * WSTR + c * 8]) = bh.s;
        }
      }
      if (t < 7) {
        const int k0 = (t + 1) * 32;
#pragma unroll
        for (int j = 0; j < 4; ++j) ax[j] = Xb[(size_t)(k0 + akg + j) * NQ];
#pragma unroll
        for (int c = 0; c < 4; ++c) {
          wp[c][0] = *(const float4*)(Wr + k0 + c * 8);
          wp[c][1] = *(const float4*)(Wr + k0 + c * 8 + 4);
        }
      }
      __syncthreads();
      bf16x8 af[2];
#pragma unroll
      for (int mi = 0; mi < 2; ++mi)
        af[mi] = *(const bf16x8*)(&As[(mi * 16 + am) * WSTR + kq]);
#pragma unroll
      for (int oj = 0; oj < 4; ++oj) {
        bf16x8 bf = *(const bf16x8*)(&Ws[(o0w + oj * 16 + am) * WSTR + kq]);
#pragma unroll
        for (int mi = 0; mi < 2; ++mi)
          acc[mi][oj] = __builtin_amdgcn_mfma_f32_16x16x32_bf16(af[mi], bf, acc[mi][oj], 0, 0, 0);
      }
    }
#pragma unroll
    for (int oj = 0; oj < 4; ++oj) {
      const int o = o0w + oj * 16 + am;
      const int h = o >> 5, d = o & 31;
      const float bias = b_val[o];
      ushort* dst = vproj + ((size_t)(b * NHC + h) * NQ) * HDC + d;
#pragma unroll
      for (int mi = 0; mi < 2; ++mi) {
        const int nb = n0 + mi * 16 + row4;
#pragma unroll
        for (int r = 0; r < 4; ++r)
          dst[(size_t)(nb + r) * HDC] = f2bf(acc[mi][oj][r] + bias);
      }
    }
  }
}

// ---------------------------------------------------------------------------
// Sampling (unchanged from R4 champion): Phase A softmax+coefs once per
// (q,p) into LDS; Phase B uint4 (8 bf16 ch) gathers. 64 queries/block.
// ---------------------------------------------------------------------------
__global__ __launch_bounds__(256) void k_sample(
    const float* __restrict__ loc, const float* __restrict__ attL,
    const ushort* __restrict__ vproj, ushort* __restrict__ msda) {
  __shared__ float4 Lc[64][9];
  __shared__ int4   Lo[64][9];
  const int b = blockIdx.z, h = blockIdx.y;
  const int tid = threadIdx.x;
  const int n0 = blockIdx.x * 64;
#pragma unroll
  for (int it = 0; it < 2; ++it) {
    const int idx = it * 256 + tid;
    const int q = idx >> 3, p = idx & 7;
    const int n = n0 + q;
    const float lg = attL[((size_t)b * NQ + n) * 64 + h * 8 + p];
    float m = lg;
#pragma unroll
    for (int off = 1; off < 8; off <<= 1) m = fmaxf(m, __shfl_xor(m, off, 64));
    const float e = __expf(lg - m);
    float s = e;
#pragma unroll
    for (int off = 1; off < 8; off <<= 1) s += __shfl_xor(s, off, 64);
    const float w = e / s;
    const float2 xy = *(const float2*)(loc + ((size_t)b * NQ + n) * 128 + h * 16 + p * 2);
    const float x = xy.x * 64.0f - 0.5f;
    const float y = xy.y * 64.0f - 0.5f;
    const float x0f = floorf(x), y0f = floorf(y);
    const float wx = x - x0f, wy = y - y0f;
    const int x0 = (int)x0f, y0 = (int)y0f;
    const int x1 = x0 + 1, y1 = y0 + 1;
    const float fx0 = (x0 >= 0 && x0 < WC) ? 1.f : 0.f;
    const float fx1 = (x1 >= 0 && x1 < WC) ? 1.f : 0.f;
    const float fy0 = (y0 >= 0 && y0 < HC) ? 1.f : 0.f;
    const float fy1 = (y1 >= 0 && y1 < HC) ? 1.f : 0.f;
    const int cx0 = min(max(x0, 0), WC - 1), cx1 = min(max(x1, 0), WC - 1);
    const int cy0 = min(max(y0, 0), HC - 1), cy1 = min(max(y1, 0), HC - 1);
    float4 cf;
    cf.x = w * (1.f - wx) * (1.f - wy) * fx0 * fy0;
    cf.y = w * wx * (1.f - wy) * fx1 * fy0;
    cf.z = w * (1.f - wx) * wy * fx0 * fy1;
    cf.w = w * wx * wy * fx1 * fy1;
    int4 of;
    of.x = (cy0 * WC + cx0) * HDC; of.y = (cy0 * WC + cx1) * HDC;
    of.z = (cy1 * WC + cx0) * HDC; of.w = (cy1 * WC + cx1) * HDC;
    Lc[q][p] = cf; Lo[q][p] = of;
  }
  __syncthreads();
  const int q = tid >> 2, d8 = (tid & 3) * 8;
  const int n = n0 + q;
  const ushort* vb = vproj + (size_t)((b * NHC + h) * NQ) * HDC + d8;
  float a[8] = {};
#pragma unroll
  for (int p = 0; p < 8; ++p) {
    const int4 of = Lo[q][p];
    const float4 cf = Lc[q][p];
    const uint4 u00 = *(const uint4*)(vb + of.x);
    const uint4 u01 = *(const uint4*)(vb + of.y);
    const uint4 u10 = *(const uint4*)(vb + of.z);
    const uint4 u11 = *(const uint4*)(vb + of.w);
    const unsigned c00[4] = {u00.x, u00.y, u00.z, u00.w};
    const unsigned c01[4] = {u01.x, u01.y, u01.z, u01.w};
    const unsigned c10[4] = {u10.x, u10.y, u10.z, u10.w};
    const unsigned c11[4] = {u11.x, u11.y, u11.z, u11.w};
#pragma unroll
    for (int j = 0; j < 4; ++j) {
      a[2 * j]     += cf.x * bflo(c00[j]) + cf.y * bflo(c01[j]) + cf.z * bflo(c10[j]) + cf.w * bflo(c11[j]);
      a[2 * j + 1] += cf.x * bfhi(c00[j]) + cf.y * bfhi(c01[j]) + cf.z * bfhi(c10[j]) + cf.w * bfhi(c11[j]);
    }
  }
  bfr8 r;
#pragma unroll
  for (int j = 0; j < 8; ++j) r.u[j] = f2bf(a[j]);
  *(s8v*)(msda + ((size_t)b * NQ + n) * DIMC + h * HDC + d8) = r.s;
}

// ---------------------------------------------------------------------------
// GEMM 3: out = msda @ W_out^T + b_out. Block = 32n x ALL 256 o (msda read
// once). Same BK=32 pipeline; A is bf16 already (no conversion).
// ---------------------------------------------------------------------------
__global__ __launch_bounds__(256) void k_out(
    const ushort* __restrict__ msda, const float* __restrict__ W_out,
    const float* __restrict__ b_out, float* __restrict__ out) {
  __shared__ __align__(16) ushort smem[11520];
  ushort* As = smem;            // 32 x WSTR
  ushort* Ws = smem + 1280;     // 256 x WSTR
  const int tid = threadIdx.x, b = blockIdx.z, n0 = blockIdx.x * 32;
  const int lane = tid & 63, wid = tid >> 6;
  const int am = lane & 15, kq = (lane >> 4) * 8, row4 = (lane >> 4) * 4;

  const int an = tid & 31, akh = ((tid >> 5) & 3) * 8;  // for tid<128
  const ushort* Ap = msda + ((size_t)b * NQ + n0 + an) * DIMC + akh;
  const float* Wr = W_out + (size_t)tid * DIMC;

  s8v av = {};
  if (tid < 128) av = *(const s8v*)(Ap);
  float4 wp[4][2];
#pragma unroll
  for (int c = 0; c < 4; ++c) {
    wp[c][0] = *(const float4*)(Wr + c * 8);
    wp[c][1] = *(const float4*)(Wr + c * 8 + 4);
  }
  const int o0w = wid * 64;
  f4 acc[2][4];
#pragma unroll
  for (int mi = 0; mi < 2; ++mi)
#pragma unroll
    for (int oj = 0; oj < 4; ++oj) acc[mi][oj] = (f4)0.f;

  for (int t = 0; t < 8; ++t) {
    __syncthreads();
    if (tid < 128) *(s8v*)(&As[an * WSTR + akh]) = av;
#pragma unroll
    for (int c = 0; c < 4; ++c) {
      const float wt[8] = {wp[c][0].x, wp[c][0].y, wp[c][0].z, wp[c][0].w,
                           wp[c][1].x, wp[c][1].y, wp[c][1].z, wp[c][1].w};
      bfr8 bh;
#pragma unroll
      for (int j = 0; j < 8; ++j) bh.u[j] = f2bf(wt[j]);
      *(s8v*)(&Ws[tid * WSTR + c * 8]) = bh.s;
    }
    if (t < 7) {
      const int k0 = (t + 1) * 32;
      if (tid < 128) av = *(const s8v*)(Ap + k0);
#pragma unroll
      for (int c = 0; c < 4; ++c) {
        wp[c][0] = *(const float4*)(Wr + k0 + c * 8);
        wp[c][1] = *(const float4*)(Wr + k0 + c * 8 + 4);
      }
    }
    __syncthreads();
    bf16x8 af[2];
#pragma unroll
    for (int mi = 0; mi < 2; ++mi)
      af[mi] = *(const bf16x8*)(&As[(mi * 16 + am) * WSTR + kq]);
#pragma unroll
    for (int oj = 0; oj < 4; ++oj) {
      bf16x8 bf = *(const bf16x8*)(&Ws[(o0w + oj * 16 + am) * WSTR + kq]);
#pragma unroll
      for (int mi = 0; mi < 2; ++mi)
        acc[mi][oj] = __builtin_amdgcn_mfma_f32_16x16x32_bf16(af[mi], bf, acc[mi][oj], 0, 0, 0);
    }
  }
#pragma unroll
  for (int oj = 0; oj < 4; ++oj) {
    const int o = o0w + oj * 16 + am;
    const float bias = b_out[o];
#pragma unroll
    for (int mi = 0; mi < 2; ++mi) {
      const int nb = n0 + mi * 16 + row4;
#pragma unroll
      for (int r = 0; r < 4; ++r)
        out[((size_t)b * NQ + nb + r) * DIMC + o] = acc[mi][oj][r] + bias;
    }
  }
}

extern "C" void kernel_launch(void* const* d_in, const int* in_sizes, int n_in,
                              void* d_out, int out_size, void* d_ws, size_t ws_size,
                              hipStream_t stream) {
  const float* query = (const float*)d_in[0];
  const float* value = (const float*)d_in[1];
  const float* W_loc = (const float*)d_in[2];
  const float* b_loc = (const float*)d_in[3];
  const float* W_att = (const float*)d_in[4];
  const float* b_att = (const float*)d_in[5];
  const float* W_val = (const float*)d_in[6];
  const float* b_val = (const float*)d_in[7];
  const float* W_out = (const float*)d_in[8];
  const float* b_out = (const float*)d_in[9];
  float* out = (float*)d_out;

  float* ws = (float*)d_ws;
  float* loc    = ws;                                     // 4*4096*128 f32
  float* att    = loc + (size_t)BC * NQ * 128;            // 4*4096*64 f32
  ushort* vproj = (ushort*)(att + (size_t)BC * NQ * 64);  // bf16 [b][h][n][d]
  ushort* msda  = vproj + (size_t)BC * NHC * NQ * HDC;    // bf16 [b][n][256]

  dim3 blk(256);
  k_proj  <<<dim3(NQ / 32, 2, BC), blk, 0, stream>>>(query, value, W_loc, b_loc,
             W_att, b_att, W_val, b_val, loc, att, vproj);
  k_sample<<<dim3(NQ / 64, NHC, BC), blk, 0, stream>>>(loc, att, vproj, msda);
  k_out   <<<dim3(NQ / 32, 1, BC), blk, 0, stream>>>(msda, W_out, b_out, out);
}

// Round 8
// 127.948 us; speedup vs baseline: 1.2445x; 1.2445x over previous
//
#include <hip/hip_runtime.h>
#include <hip/hip_bf16.h>
#include <math.h>

#define NQ   4096
#define DIMC 256
#define NHC  8
#define NPC  8
#define HDC  32
#define HC   64
#define WC   64
#define BC   4
#define LSTR 40   // LDS row stride in ushorts (80 B: 16B-aligned)

typedef __bf16 bf16x8 __attribute__((ext_vector_type(8)));
typedef __attribute__((ext_vector_type(4))) float f4;
typedef __attribute__((ext_vector_type(8))) short s8v;

__device__ __forceinline__ ushort f2bf(float f) {
  __hip_bfloat16 h = __float2bfloat16(f);
  union { __hip_bfloat16 h; ushort u; } c; c.h = h; return c.u;
}
__device__ __forceinline__ float bfu2f(ushort u) {
  union { unsigned i; float f; } c; c.i = ((unsigned)u) << 16; return c.f;
}
__device__ __forceinline__ float bflo(unsigned u) {
  union { unsigned i; float f; } c; c.i = u << 16; return c.f;
}
__device__ __forceinline__ float bfhi(unsigned u) {
  union { unsigned i; float f; } c; c.i = u & 0xffff0000u; return c.f;
}

union bfr8 { ushort u[8]; bf16x8 v; s8v s; };

// ---------------------------------------------------------------------------
// k_proj: R4's k_locatt (y in [0,2], split-precision 3-pass MFMA) and
// k_vproj (y in [3,6], plain bf16 MFMA) bodies VERBATIM, merged into one
// launch so the two independent GEMMs co-schedule (tail/head overlap, one
// less launch gap). Tile 64n x 64o, BK=32, register-prefetch pipeline.
// ---------------------------------------------------------------------------
__global__ __launch_bounds__(256) void k_proj(
    const float* __restrict__ query, const float* __restrict__ value,
    const float* __restrict__ W_loc, const float* __restrict__ b_loc,
    const float* __restrict__ W_att, const float* __restrict__ b_att,
    const float* __restrict__ W_val, const float* __restrict__ b_val,
    float* __restrict__ loc, float* __restrict__ att,
    ushort* __restrict__ vproj) {
  __shared__ __align__(16) ushort smem[4 * 64 * LSTR];  // 20.5 KB
  const int tid = threadIdx.x;
  const int b = blockIdx.z, n0 = blockIdx.x * 64;
  const int lane = tid & 63, wid = tid >> 6;
  const int wn0 = (wid & 1) * 32, wo0 = (wid >> 1) * 32;
  const int am = lane & 15, kq = (lane >> 4) * 8;
  const int an = tid & 63, ak = (tid >> 6) * 8;
  const int wo = tid >> 2, wk = (tid & 3) * 8;

  f4 acc[2][2];
#pragma unroll
  for (int mi = 0; mi < 2; ++mi) { acc[mi][0] = (f4)0.f; acc[mi][1] = (f4)0.f; }

  if (blockIdx.y < 3) {
    // ================= loc/att: split-precision (R4 k_locatt) ============
    ushort* Ah = smem;
    ushort* Al = smem + 64 * LSTR;
    ushort* Wh = smem + 2 * 64 * LSTR;
    ushort* Wl = smem + 3 * 64 * LSTR;
    const int o0 = blockIdx.y * 64;
    const float* Xb = query + (size_t)b * DIMC * NQ + n0 + an;
    const int oo = o0 + wo;
    const float* Wrow = (oo < 128) ? (W_loc + (size_t)oo * DIMC)
                                   : (W_att + (size_t)(oo - 128) * DIMC);
    float ax[8];
    float4 wx0, wx1;
#pragma unroll
    for (int j = 0; j < 8; ++j) ax[j] = Xb[(size_t)(ak + j) * NQ];
    wx0 = *(const float4*)(Wrow + wk);
    wx1 = *(const float4*)(Wrow + wk + 4);

    for (int t = 0; t < 8; ++t) {
      __syncthreads();
      {
        bfr8 ph, pl;
#pragma unroll
        for (int j = 0; j < 8; ++j) {
          ushort h = f2bf(ax[j]);
          ph.u[j] = h;
          pl.u[j] = f2bf(ax[j] - bfu2f(h));
        }
        *(s8v*)(&Ah[an * LSTR + ak]) = ph.s;
        *(s8v*)(&Al[an * LSTR + ak]) = pl.s;
        float wt[8] = {wx0.x, wx0.y, wx0.z, wx0.w, wx1.x, wx1.y, wx1.z, wx1.w};
        bfr8 qh, ql;
#pragma unroll
        for (int j = 0; j < 8; ++j) {
          ushort h = f2bf(wt[j]);
          qh.u[j] = h;
          ql.u[j] = f2bf(wt[j] - bfu2f(h));
        }
        *(s8v*)(&Wh[wo * LSTR + wk]) = qh.s;
        *(s8v*)(&Wl[wo * LSTR + wk]) = ql.s;
      }
      if (t < 7) {
        const int k0 = (t + 1) * 32;
#pragma unroll
        for (int j = 0; j < 8; ++j) ax[j] = Xb[(size_t)(k0 + ak + j) * NQ];
        wx0 = *(const float4*)(Wrow + k0 + wk);
        wx1 = *(const float4*)(Wrow + k0 + wk + 4);
      }
      __syncthreads();
      bf16x8 ah[2], al[2], bh[2], bl[2];
#pragma unroll
      for (int mi = 0; mi < 2; ++mi) {
        ah[mi] = *(const bf16x8*)(&Ah[(wn0 + mi * 16 + am) * LSTR + kq]);
        al[mi] = *(const bf16x8*)(&Al[(wn0 + mi * 16 + am) * LSTR + kq]);
      }
#pragma unroll
      for (int oj = 0; oj < 2; ++oj) {
        bh[oj] = *(const bf16x8*)(&Wh[(wo0 + oj * 16 + am) * LSTR + kq]);
        bl[oj] = *(const bf16x8*)(&Wl[(wo0 + oj * 16 + am) * LSTR + kq]);
      }
#pragma unroll
      for (int mi = 0; mi < 2; ++mi)
#pragma unroll
        for (int oj = 0; oj < 2; ++oj) {
          acc[mi][oj] = __builtin_amdgcn_mfma_f32_16x16x32_bf16(ah[mi], bh[oj], acc[mi][oj], 0, 0, 0);
          acc[mi][oj] = __builtin_amdgcn_mfma_f32_16x16x32_bf16(al[mi], bh[oj], acc[mi][oj], 0, 0, 0);
          acc[mi][oj] = __builtin_amdgcn_mfma_f32_16x16x32_bf16(ah[mi], bl[oj], acc[mi][oj], 0, 0, 0);
        }
    }
    const int o0l = blockIdx.y * 64;
    const bool isAtt = (o0l >= 128);
    float* dstBase = isAtt ? att : loc;
    const float* bias = isAtt ? b_att : b_loc;
    const int ostride = isAtt ? 64 : 128;
    const int ob = isAtt ? o0l - 128 : o0l;
#pragma unroll
    for (int oj = 0; oj < 2; ++oj) {
      const int o = ob + wo0 + oj * 16 + am;
      const float bv = bias[o];
#pragma unroll
      for (int mi = 0; mi < 2; ++mi) {
        const int nb = n0 + wn0 + mi * 16 + (lane >> 4) * 4;
#pragma unroll
        for (int r = 0; r < 4; ++r)
          dstBase[((size_t)b * NQ + nb + r) * ostride + o] = acc[mi][oj][r] + bv;
      }
    }
  } else {
    // ================= value projection (R4 k_vproj) =====================
    ushort* As = smem;
    ushort* Ws = smem + 64 * LSTR;
    const int o0 = (blockIdx.y - 3) * 64;
    const float* Xb = value + (size_t)b * DIMC * NQ + n0 + an;
    const float* Wrow = W_val + (size_t)(o0 + wo) * DIMC;

    float ax[8];
    float4 wx0, wx1;
#pragma unroll
    for (int j = 0; j < 8; ++j) ax[j] = Xb[(size_t)(ak + j) * NQ];
    wx0 = *(const float4*)(Wrow + wk);
    wx1 = *(const float4*)(Wrow + wk + 4);

    for (int t = 0; t < 8; ++t) {
      __syncthreads();
      {
        bfr8 pa;
#pragma unroll
        for (int j = 0; j < 8; ++j) pa.u[j] = f2bf(ax[j]);
        *(s8v*)(&As[an * LSTR + ak]) = pa.s;
        float wt[8] = {wx0.x, wx0.y, wx0.z, wx0.w, wx1.x, wx1.y, wx1.z, wx1.w};
        bfr8 pw;
#pragma unroll
        for (int j = 0; j < 8; ++j) pw.u[j] = f2bf(wt[j]);
        *(s8v*)(&Ws[wo * LSTR + wk]) = pw.s;
      }
      if (t < 7) {
        const int k0 = (t + 1) * 32;
#pragma unroll
        for (int j = 0; j < 8; ++j) ax[j] = Xb[(size_t)(k0 + ak + j) * NQ];
        wx0 = *(const float4*)(Wrow + k0 + wk);
        wx1 = *(const float4*)(Wrow + k0 + wk + 4);
      }
      __syncthreads();
      bf16x8 af[2], bf[2];
#pragma unroll
      for (int mi = 0; mi < 2; ++mi)
        af[mi] = *(const bf16x8*)(&As[(wn0 + mi * 16 + am) * LSTR + kq]);
#pragma unroll
      for (int oj = 0; oj < 2; ++oj)
        bf[oj] = *(const bf16x8*)(&Ws[(wo0 + oj * 16 + am) * LSTR + kq]);
#pragma unroll
      for (int mi = 0; mi < 2; ++mi)
#pragma unroll
        for (int oj = 0; oj < 2; ++oj)
          acc[mi][oj] = __builtin_amdgcn_mfma_f32_16x16x32_bf16(af[mi], bf[oj], acc[mi][oj], 0, 0, 0);
    }
#pragma unroll
    for (int oj = 0; oj < 2; ++oj) {
      const int o = o0 + wo0 + oj * 16 + am;
      const int h = o >> 5, d = o & 31;
      const float bias = b_val[o];
      ushort* dst = vproj + ((size_t)(b * NHC + h) * NQ) * HDC + d;
#pragma unroll
      for (int mi = 0; mi < 2; ++mi) {
        const int nb = n0 + wn0 + mi * 16 + (lane >> 4) * 4;
#pragma unroll
        for (int r = 0; r < 4; ++r)
          dst[(size_t)(nb + r) * HDC] = f2bf(acc[mi][oj][r] + bias);
      }
    }
  }
}

// ---------------------------------------------------------------------------
// Sampling (R4 verbatim): Phase A softmax+coefs once per (q,p) into LDS;
// Phase B uint4 (8 bf16 ch) gathers. 64 queries/block.
// ---------------------------------------------------------------------------
__global__ __launch_bounds__(256) void k_sample(
    const float* __restrict__ loc, const float* __restrict__ attL,
    const ushort* __restrict__ vproj, ushort* __restrict__ msda) {
  __shared__ float4 Lc[64][9];
  __shared__ int4   Lo[64][9];
  const int b = blockIdx.z, h = blockIdx.y;
  const int tid = threadIdx.x;
  const int n0 = blockIdx.x * 64;
#pragma unroll
  for (int it = 0; it < 2; ++it) {
    const int idx = it * 256 + tid;
    const int q = idx >> 3, p = idx & 7;
    const int n = n0 + q;
    const float lg = attL[((size_t)b * NQ + n) * 64 + h * 8 + p];
    float m = lg;
#pragma unroll
    for (int off = 1; off < 8; off <<= 1) m = fmaxf(m, __shfl_xor(m, off, 64));
    const float e = __expf(lg - m);
    float s = e;
#pragma unroll
    for (int off = 1; off < 8; off <<= 1) s += __shfl_xor(s, off, 64);
    const float w = e / s;
    const float2 xy = *(const float2*)(loc + ((size_t)b * NQ + n) * 128 + h * 16 + p * 2);
    const float x = xy.x * 64.0f - 0.5f;
    const float y = xy.y * 64.0f - 0.5f;
    const float x0f = floorf(x), y0f = floorf(y);
    const float wx = x - x0f, wy = y - y0f;
    const int x0 = (int)x0f, y0 = (int)y0f;
    const int x1 = x0 + 1, y1 = y0 + 1;
    const float fx0 = (x0 >= 0 && x0 < WC) ? 1.f : 0.f;
    const float fx1 = (x1 >= 0 && x1 < WC) ? 1.f : 0.f;
    const float fy0 = (y0 >= 0 && y0 < HC) ? 1.f : 0.f;
    const float fy1 = (y1 >= 0 && y1 < HC) ? 1.f : 0.f;
    const int cx0 = min(max(x0, 0), WC - 1), cx1 = min(max(x1, 0), WC - 1);
    const int cy0 = min(max(y0, 0), HC - 1), cy1 = min(max(y1, 0), HC - 1);
    float4 cf;
    cf.x = w * (1.f - wx) * (1.f - wy) * fx0 * fy0;
    cf.y = w * wx * (1.f - wy) * fx1 * fy0;
    cf.z = w * (1.f - wx) * wy * fx0 * fy1;
    cf.w = w * wx * wy * fx1 * fy1;
    int4 of;
    of.x = (cy0 * WC + cx0) * HDC; of.y = (cy0 * WC + cx1) * HDC;
    of.z = (cy1 * WC + cx0) * HDC; of.w = (cy1 * WC + cx1) * HDC;
    Lc[q][p] = cf; Lo[q][p] = of;
  }
  __syncthreads();
  const int q = tid >> 2, d8 = (tid & 3) * 8;
  const int n = n0 + q;
  const ushort* vb = vproj + (size_t)((b * NHC + h) * NQ) * HDC + d8;
  float a[8] = {};
#pragma unroll
  for (int p = 0; p < 8; ++p) {
    const int4 of = Lo[q][p];
    const float4 cf = Lc[q][p];
    const uint4 u00 = *(const uint4*)(vb + of.x);
    const uint4 u01 = *(const uint4*)(vb + of.y);
    const uint4 u10 = *(const uint4*)(vb + of.z);
    const uint4 u11 = *(const uint4*)(vb + of.w);
    const unsigned c00[4] = {u00.x, u00.y, u00.z, u00.w};
    const unsigned c01[4] = {u01.x, u01.y, u01.z, u01.w};
    const unsigned c10[4] = {u10.x, u10.y, u10.z, u10.w};
    const unsigned c11[4] = {u11.x, u11.y, u11.z, u11.w};
#pragma unroll
    for (int j = 0; j < 4; ++j) {
      a[2 * j]     += cf.x * bflo(c00[j]) + cf.y * bflo(c01[j]) + cf.z * bflo(c10[j]) + cf.w * bflo(c11[j]);
      a[2 * j + 1] += cf.x * bfhi(c00[j]) + cf.y * bfhi(c01[j]) + cf.z * bfhi(c10[j]) + cf.w * bfhi(c11[j]);
    }
  }
  bfr8 r;
#pragma unroll
  for (int j = 0; j < 8; ++j) r.u[j] = f2bf(a[j]);
  *(s8v*)(msda + ((size_t)b * NQ + n) * DIMC + h * HDC + d8) = r.s;
}

// ---------------------------------------------------------------------------
// GEMM 3 (R4 verbatim): out = msda @ W_out^T + b_out. BK=32 pipeline.
// ---------------------------------------------------------------------------
__global__ __launch_bounds__(256) void k_out(
    const ushort* __restrict__ msda, const float* __restrict__ W_out,
    const float* __restrict__ b_out, float* __restrict__ out) {
  __shared__ __align__(16) ushort As[64 * LSTR];
  __shared__ __align__(16) ushort Ws[64 * LSTR];
  const int b = blockIdx.z, n0 = blockIdx.x * 64, o0 = blockIdx.y * 64;
  const int tid = threadIdx.x, lane = tid & 63, wid = tid >> 6;
  const int wn0 = (wid & 1) * 32, wo0 = (wid >> 1) * 32;
  const int am = lane & 15, kq = (lane >> 4) * 8;
  const int ar = tid >> 2, akq = (tid & 3) * 8;
  const int wo = tid >> 2, wk = (tid & 3) * 8;
  const ushort* Ab = msda + ((size_t)b * NQ + n0 + ar) * DIMC + akq;
  const float* Wrow = W_out + (size_t)(o0 + wo) * DIMC;

  f4 acc[2][2];
#pragma unroll
  for (int mi = 0; mi < 2; ++mi) { acc[mi][0] = (f4)0.f; acc[mi][1] = (f4)0.f; }

  s8v aval = *(const s8v*)(Ab);
  float4 wx0 = *(const float4*)(Wrow + wk);
  float4 wx1 = *(const float4*)(Wrow + wk + 4);

  for (int t = 0; t < 8; ++t) {
    __syncthreads();
    *(s8v*)(&As[ar * LSTR + akq]) = aval;
    {
      float wt[8] = {wx0.x, wx0.y, wx0.z, wx0.w, wx1.x, wx1.y, wx1.z, wx1.w};
      bfr8 pw;
#pragma unroll
      for (int j = 0; j < 8; ++j) pw.u[j] = f2bf(wt[j]);
      *(s8v*)(&Ws[wo * LSTR + wk]) = pw.s;
    }
    if (t < 7) {
      const int k0 = (t + 1) * 32;
      aval = *(const s8v*)(Ab + k0);
      wx0 = *(const float4*)(Wrow + k0 + wk);
      wx1 = *(const float4*)(Wrow + k0 + wk + 4);
    }
    __syncthreads();
    bf16x8 af[2], bf[2];
#pragma unroll
    for (int mi = 0; mi < 2; ++mi)
      af[mi] = *(const bf16x8*)(&As[(wn0 + mi * 16 + am) * LSTR + kq]);
#pragma unroll
    for (int oj = 0; oj < 2; ++oj)
      bf[oj] = *(const bf16x8*)(&Ws[(wo0 + oj * 16 + am) * LSTR + kq]);
#pragma unroll
    for (int mi = 0; mi < 2; ++mi)
#pragma unroll
      for (int oj = 0; oj < 2; ++oj)
        acc[mi][oj] = __builtin_amdgcn_mfma_f32_16x16x32_bf16(af[mi], bf[oj], acc[mi][oj], 0, 0, 0);
  }
#pragma unroll
  for (int oj = 0; oj < 2; ++oj) {
    const int o = o0 + wo0 + oj * 16 + am;
    const float bias = b_out[o];
#pragma unroll
    for (int mi = 0; mi < 2; ++mi) {
      const int nb = n0 + wn0 + mi * 16 + (lane >> 4) * 4;
#pragma unroll
      for (int r = 0; r < 4; ++r)
        out[((size_t)b * NQ + nb + r) * DIMC + o] = acc[mi][oj][r] + bias;
    }
  }
}

extern "C" void kernel_launch(void* const* d_in, const int* in_sizes, int n_in,
                              void* d_out, int out_size, void* d_ws, size_t ws_size,
                              hipStream_t stream) {
  const float* query = (const float*)d_in[0];
  const float* value = (const float*)d_in[1];
  const float* W_loc = (const float*)d_in[2];
  const float* b_loc = (const float*)d_in[3];
  const float* W_att = (const float*)d_in[4];
  const float* b_att = (const float*)d_in[5];
  const float* W_val = (const float*)d_in[6];
  const float* b_val = (const float*)d_in[7];
  const float* W_out = (const float*)d_in[8];
  const float* b_out = (const float*)d_in[9];
  float* out = (float*)d_out;

  float* ws = (float*)d_ws;
  float* loc    = ws;                                     // 4*4096*128 f32
  float* att    = loc + (size_t)BC * NQ * 128;            // 4*4096*64 f32
  ushort* vproj = (ushort*)(att + (size_t)BC * NQ * 64);  // bf16 [b][h][n][d]
  ushort* msda  = vproj + (size_t)BC * NHC * NQ * HDC;    // bf16 [b][n][256]

  dim3 blk(256);
  k_proj  <<<dim3(NQ / 64, 7, BC), blk, 0, stream>>>(query, value, W_loc, b_loc,
             W_att, b_att, W_val, b_val, loc, att, vproj);
  k_sample<<<dim3(NQ / 64, NHC, BC), blk, 0, stream>>>(loc, att, vproj, msda);
  k_out   <<<dim3(NQ / 64, 4, BC), blk, 0, stream>>>(msda, W_out, b_out, out);
}